// Round 1
// baseline (5894.500 us; speedup 1.0000x reference)
//
#include <hip/hip_runtime.h>
#include <math.h>

#define B_  64
#define T_  2048
#define V_  512
#define H_  256
#define D_  128
#define VD_ 8

// ---------------------------------------------------------------------------
// Generic NT GEMM: C[m,n] = bias[n] + sum_k A[m,k] * B[n,k]
// A: M x K row-major, B: N x K row-major, C: M x N row-major.
// Block = 256 threads, tile 64(M) x 256(N), K staged in chunks of 32.
// Thread (tm=tid>>4, tn=tid&15) computes rows 4*tm..+3, cols {64*cb + 4*tn + j}.
// Column interleave keeps Bs b128 reads conflict-free (consecutive lanes ->
// consecutive float4).
// ---------------------------------------------------------------------------
__global__ __launch_bounds__(256) void gemm_nt_kernel(
    const float* __restrict__ A, const float* __restrict__ Bm,
    const float* __restrict__ bias, float* __restrict__ C,
    int M, int N, int K)
{
    __shared__ float As[32][68];    // +4 pad keeps 16B alignment, breaks stride alias
    __shared__ float Bs[32][260];

    const int m0  = blockIdx.x * 64;
    const int n0  = blockIdx.y * 256;
    const int tid = threadIdx.x;
    const int tm  = tid >> 4;   // 0..15
    const int tn  = tid & 15;   // 0..15

    float acc[4][4][4];
    #pragma unroll
    for (int i = 0; i < 4; i++)
      #pragma unroll
      for (int cb = 0; cb < 4; cb++)
        #pragma unroll
        for (int jj = 0; jj < 4; jj++) acc[i][cb][jj] = 0.f;

    for (int kc = 0; kc < K; kc += 32) {
        // stage A tile: 64 rows x 32 k  (512 float4, 2 per thread)
        #pragma unroll
        for (int rep = 0; rep < 2; rep++) {
            int f  = tid + rep * 256;
            int mm = f >> 3;
            int k4 = (f & 7) << 2;
            float4 v = *(const float4*)(A + (size_t)(m0 + mm) * K + kc + k4);
            As[k4 + 0][mm] = v.x;
            As[k4 + 1][mm] = v.y;
            As[k4 + 2][mm] = v.z;
            As[k4 + 3][mm] = v.w;
        }
        // stage B tile: 256 rows x 32 k  (2048 float4, 8 per thread)
        #pragma unroll
        for (int rep = 0; rep < 8; rep++) {
            int f  = tid + rep * 256;
            int nn = f >> 3;
            int k4 = (f & 7) << 2;
            float4 v = *(const float4*)(Bm + (size_t)(n0 + nn) * K + kc + k4);
            Bs[k4 + 0][nn] = v.x;
            Bs[k4 + 1][nn] = v.y;
            Bs[k4 + 2][nn] = v.z;
            Bs[k4 + 3][nn] = v.w;
        }
        __syncthreads();

        #pragma unroll
        for (int kk = 0; kk < 32; kk++) {
            float4 a = *(const float4*)&As[kk][4 * tm];   // broadcast (4 addrs/wave)
            #pragma unroll
            for (int cb = 0; cb < 4; cb++) {
                float4 b = *(const float4*)&Bs[kk][64 * cb + 4 * tn];
                acc[0][cb][0] += a.x * b.x; acc[0][cb][1] += a.x * b.y;
                acc[0][cb][2] += a.x * b.z; acc[0][cb][3] += a.x * b.w;
                acc[1][cb][0] += a.y * b.x; acc[1][cb][1] += a.y * b.y;
                acc[1][cb][2] += a.y * b.z; acc[1][cb][3] += a.y * b.w;
                acc[2][cb][0] += a.z * b.x; acc[2][cb][1] += a.z * b.y;
                acc[2][cb][2] += a.z * b.z; acc[2][cb][3] += a.z * b.w;
                acc[3][cb][0] += a.w * b.x; acc[3][cb][1] += a.w * b.y;
                acc[3][cb][2] += a.w * b.z; acc[3][cb][3] += a.w * b.w;
            }
        }
        __syncthreads();
    }

    #pragma unroll
    for (int cb = 0; cb < 4; cb++) {
        int c = n0 + 64 * cb + 4 * tn;
        float4 bv;
        if (bias) bv = *(const float4*)(bias + c);
        else      bv = make_float4(0.f, 0.f, 0.f, 0.f);
        #pragma unroll
        for (int i = 0; i < 4; i++) {
            int r = m0 + 4 * tm + i;
            float4 v = make_float4(acc[i][cb][0] + bv.x, acc[i][cb][1] + bv.y,
                                   acc[i][cb][2] + bv.z, acc[i][cb][3] + bv.w);
            *(float4*)(C + (size_t)r * N + c) = v;
        }
    }
}

// ---------------------------------------------------------------------------
// Recurrence: one block per batch element, 512 threads (8 waves).
// Thread (j = tid&255, half = tid>>8) holds W_hh[j][half*128 .. +128) in VGPRs.
// Per step: h_tilde -> LDS -> half-row dot (128 FMA/thread) -> combine halves
// -> tanh -> store hidden -> wave0 computes a (softmax3) + n (sigmoid8)
// -> double-buffered stack blend in LDS.
// ---------------------------------------------------------------------------
__global__ __launch_bounds__(512, 2) void recurrence_kernel(
    const float* __restrict__ Z,        // (B,T,H)
    const float* __restrict__ stack0,   // (B,D,VD)
    const float* __restrict__ hidden0,  // (B,H)
    const float* __restrict__ W_hh,     // (H,H)
    const float* __restrict__ b_hh,     // (H)
    const float* __restrict__ W_sh,     // (H,VD)
    const float* __restrict__ W_a,      // (3,H)
    const float* __restrict__ W_n,      // (VD,H)
    float* __restrict__ H_all,          // (B,T,H)
    float* __restrict__ out_stack,      // (B,D,VD)
    float* __restrict__ out_hidden)     // (B,H)
{
    const int b    = blockIdx.x;
    const int tid  = threadIdx.x;
    const int j    = tid & 255;
    const int half = tid >> 8;

    __shared__ float sh_h[H_];
    __shared__ float sh_part[H_];
    __shared__ float sh_hnew[H_];
    __shared__ float sh_st[2][D_][VD_];
    __shared__ float sh_a[3];
    __shared__ float sh_n[VD_];
    __shared__ float sh_Wan[11 * H_];   // rows 0..2 = W_a, 3..10 = W_n

    // W_hh half-row -> 32 float4 in VGPRs (one-time, L2-served)
    float4 wreg[32];
    {
        const float4* wrow = (const float4*)(W_hh + (size_t)j * H_ + half * 128);
        #pragma unroll
        for (int q = 0; q < 32; q++) wreg[q] = wrow[q];
    }
    float wsh[VD_];
    #pragma unroll
    for (int v = 0; v < VD_; v++) wsh[v] = W_sh[j * VD_ + v];
    const float bhh = b_hh[j];

    for (int q = tid; q < D_ * VD_; q += 512)
        (&sh_st[0][0][0])[q] = stack0[(size_t)b * D_ * VD_ + q];
    for (int q = tid; q < 11 * H_; q += 512) {
        int row = q >> 8, k = q & 255;
        sh_Wan[q] = (row < 3) ? W_a[row * H_ + k] : W_n[(row - 3) * H_ + k];
    }

    float hidden_reg = 0.f;
    float z_cur = 0.f;
    if (half == 0) {
        hidden_reg = hidden0[(size_t)b * H_ + j];
        z_cur = Z[((size_t)b * T_) * H_ + j];
    }
    __syncthreads();

    for (int t = 0; t < T_; t++) {
        const int p = t & 1;

        if (half == 0) {
            float ht = hidden_reg;
            #pragma unroll
            for (int v = 0; v < VD_; v++) ht += sh_st[p][0][v] * wsh[v];
            sh_h[j] = ht;
        }
        __syncthreads();   // A: h_tilde ready

        // 128-long half-dot; sh_h reads are wave-uniform (broadcast, conflict-free)
        float p0 = 0.f, p1 = 0.f, p2 = 0.f, p3 = 0.f;
        {
            const float4* hh = (const float4*)&sh_h[half * 128];
            #pragma unroll
            for (int q = 0; q < 32; q += 4) {
                float4 h0 = hh[q + 0], h1 = hh[q + 1], h2 = hh[q + 2], h3 = hh[q + 3];
                p0 += h0.x * wreg[q+0].x + h0.y * wreg[q+0].y + h0.z * wreg[q+0].z + h0.w * wreg[q+0].w;
                p1 += h1.x * wreg[q+1].x + h1.y * wreg[q+1].y + h1.z * wreg[q+1].z + h1.w * wreg[q+1].w;
                p2 += h2.x * wreg[q+2].x + h2.y * wreg[q+2].y + h2.z * wreg[q+2].z + h2.w * wreg[q+2].w;
                p3 += h3.x * wreg[q+3].x + h3.y * wreg[q+3].y + h3.z * wreg[q+3].z + h3.w * wreg[q+3].w;
            }
        }
        float partial = (p0 + p1) + (p2 + p3);
        if (half) sh_part[j] = partial;
        __syncthreads();   // B: half-1 partials ready

        if (half == 0) {
            float pre = z_cur + bhh + partial + sh_part[j];
            float hn = tanhf(pre);
            hidden_reg = hn;
            sh_hnew[j] = hn;
            H_all[((size_t)b * T_ + t) * H_ + j] = hn;
            if (t + 1 < T_) z_cur = Z[((size_t)b * T_ + (t + 1)) * H_ + j];  // prefetch
        }
        __syncthreads();   // C: hnew ready

        if (tid < 64) {    // wave 0: 11 dots (3 gate logits + 8 n-values)
            float acc[11];
            #pragma unroll
            for (int i = 0; i < 11; i++) acc[i] = 0.f;
            #pragma unroll
            for (int qq = 0; qq < 4; qq++) {
                float hv = sh_hnew[tid + 64 * qq];
                #pragma unroll
                for (int i = 0; i < 11; i++)
                    acc[i] += hv * sh_Wan[i * H_ + tid + 64 * qq];
            }
            #pragma unroll
            for (int off = 32; off > 0; off >>= 1)
              #pragma unroll
              for (int i = 0; i < 11; i++)
                acc[i] += __shfl_xor(acc[i], off, 64);
            if (tid == 0) {
                float m  = fmaxf(acc[0], fmaxf(acc[1], acc[2]));
                float e0 = expf(acc[0] - m), e1 = expf(acc[1] - m), e2 = expf(acc[2] - m);
                float inv = 1.f / (e0 + e1 + e2);
                sh_a[0] = e0 * inv; sh_a[1] = e1 * inv; sh_a[2] = e2 * inv;
            }
            if (tid < VD_) sh_n[tid] = 1.f / (1.f + expf(-acc[3 + tid]));
        }
        __syncthreads();   // D: a, n ready

        {
            float a0 = sh_a[0], a1 = sh_a[1], a2 = sh_a[2];
            #pragma unroll
            for (int e = 0; e < 2; e++) {
                int q = tid + e * 512;
                int d = q >> 3, v = q & 7;
                float cur  = sh_st[p][d][v];
                float push = (d == 0)      ? sh_n[v] : sh_st[p][d - 1][v];
                float pop  = (d == D_ - 1) ? 0.f     : sh_st[p][d + 1][v];
                sh_st[p ^ 1][d][v] = a0 * push + a1 * pop + a2 * cur;
            }
        }
        __syncthreads();   // E: new stack ready
    }

    // T_ even -> final stack in buffer 0
    for (int q = tid; q < D_ * VD_; q += 512)
        out_stack[(size_t)b * D_ * VD_ + q] = (&sh_st[0][0][0])[q];
    if (half == 0)
        out_hidden[(size_t)b * H_ + j] = hidden_reg;
}

extern "C" void kernel_launch(void* const* d_in, const int* in_sizes, int n_in,
                              void* d_out, int out_size, void* d_ws, size_t ws_size,
                              hipStream_t stream) {
    const float* inputs  = (const float*)d_in[0];
    const float* stack0  = (const float*)d_in[1];
    const float* hidden0 = (const float*)d_in[2];
    const float* W_ih    = (const float*)d_in[3];
    const float* b_ih    = (const float*)d_in[4];
    const float* W_hh    = (const float*)d_in[5];
    const float* b_hh    = (const float*)d_in[6];
    const float* W_sh    = (const float*)d_in[7];
    const float* W_y     = (const float*)d_in[8];
    const float* W_a     = (const float*)d_in[9];
    const float* W_n     = (const float*)d_in[10];

    float* out = (float*)d_out;
    // Z staged in the outputs region of d_out (fully consumed by the
    // recurrence kernel before the post-GEMM overwrites it).
    float* Z     = out;                                   // (B,T,H) = 128 MB
    float* H_all = (float*)d_ws;                          // (B,T,H) = 128 MB
    float* out_stack  = out + (size_t)B_ * T_ * V_;
    float* out_hidden = out_stack + (size_t)B_ * D_ * VD_;

    const int M = B_ * T_;   // 131072

    // 1) Z = inputs @ W_ih^T + b_ih     (M x 256, K=512)
    gemm_nt_kernel<<<dim3(M / 64, H_ / 256), 256, 0, stream>>>(
        inputs, W_ih, b_ih, Z, M, H_, V_);

    // 2) serial scan: hidden/stack evolution, H_all written
    recurrence_kernel<<<dim3(B_), 512, 0, stream>>>(
        Z, stack0, hidden0, W_hh, b_hh, W_sh, W_a, W_n,
        H_all, out_stack, out_hidden);

    // 3) outputs = H_all @ W_y^T        (M x 512, K=256)
    gemm_nt_kernel<<<dim3(M / 64, V_ / 256), 256, 0, stream>>>(
        H_all, W_y, nullptr, out, M, V_, H_);
}